// Round 8
// baseline (659.569 us; speedup 1.0000x reference)
//
#include <hip/hip_runtime.h>
#include <stdint.h>

typedef unsigned short u16;
typedef short s16x8 __attribute__((ext_vector_type(8)));
typedef unsigned short u16x8 __attribute__((ext_vector_type(8)));
typedef float f32x4 __attribute__((ext_vector_type(4)));

#define S_LEN 2048
#define NBATCH 2
#define HID 3584
#define NH 28
#define NKV 4
#define HD 128
#define QSZ 3584
#define KVSZ 512
#define QKV_N 4608
#define RSCALE 0.08838834764831845f  // 128^-0.5

__device__ __forceinline__ u16 f2bf(float f) {
    union { float f; uint32_t u; } x; x.f = f;
    uint32_t r = x.u + 0x7FFF + ((x.u >> 16) & 1);
    return (u16)(r >> 16);
}
__device__ __forceinline__ float bf2f(u16 u) {
    union { uint32_t u; float f; } x; x.u = ((uint32_t)u) << 16;
    return x.f;
}
__device__ __forceinline__ void async_load16(const u16* g, u16* l) {
    __builtin_amdgcn_global_load_lds((const __attribute__((address_space(1))) void*)g,
                                     (__attribute__((address_space(3))) void*)l, 16, 0, 0);
}

// ---------------- fp32 -> bf16 convert ----------------
__global__ __launch_bounds__(256) void cvt_bf16_kernel(const float* __restrict__ in,
                                                       u16* __restrict__ out, int n4) {
    int i = blockIdx.x * 256 + threadIdx.x;
    if (i >= n4) return;
    float4 v = ((const float4*)in)[i];
    ushort4 o;
    o.x = f2bf(v.x); o.y = f2bf(v.y); o.z = f2bf(v.z); o.w = f2bf(v.w);
    ((ushort4*)out)[i] = o;
}

// ---------------- transpose + convert: out[c][r] = bf16(in[r][c]) ----------------
// 64x32 input tile: writes become full 128B segments (u16x8/thread); reads stay float4.
__global__ __launch_bounds__(256) void transpose_cvt_kernel(const float* __restrict__ in,
                                                            u16* __restrict__ out, int R, int C) {
    __shared__ float tile[64][33];
    int r0 = blockIdx.y * 64, c0 = blockIdx.x * 32;
    int t = threadIdx.x;
    int lr = t >> 3, lc = (t & 7) * 4;     // lr 0..31, lc 0..28
#pragma unroll
    for (int i = 0; i < 2; ++i) {
        int rr = lr + i * 32;
        float4 v = *(const float4*)&in[(size_t)(r0 + rr) * C + c0 + lc];
        tile[rr][lc + 0] = v.x; tile[rr][lc + 1] = v.y;
        tile[rr][lc + 2] = v.z; tile[rr][lc + 3] = v.w;
    }
    __syncthreads();
    int wr = t >> 3, wc = (t & 7) * 8;     // wr 0..31 (out row), wc 0..56 (out col group)
    u16x8 o;
#pragma unroll
    for (int e = 0; e < 8; ++e) o[e] = f2bf(tile[wc + e][wr]);
    *(u16x8*)&out[(size_t)(c0 + wr) * R + r0 + wc] = o;
}

// ---------------- 128x128 4-wave MFMA GEMM ----------
template <bool BIAS, bool OUTBF16>
__global__ __launch_bounds__(256) void gemm_kernel(const u16* __restrict__ A,
                                                   const u16* __restrict__ Bt,
                                                   const float* __restrict__ bias,
                                                   void* __restrict__ Cout,
                                                   int M, int N, int K) {
    __shared__ __align__(16) u16 As[128 * 64];
    __shared__ __align__(16) u16 Bs[128 * 64];
    int t = threadIdx.x;
    int w = t >> 6, l = t & 63;
    int lane16 = l & 15, quad = l >> 4;
    int m0 = blockIdx.y * 128, n0 = blockIdx.x * 128;
    int wm = (w >> 1) * 64, wn = (w & 1) * 64;

    f32x4 z = {0.f, 0.f, 0.f, 0.f};
    f32x4 acc[4][4];
#pragma unroll
    for (int i = 0; i < 4; ++i)
#pragma unroll
        for (int j = 0; j < 4; ++j) acc[i][j] = z;

    int srow = l >> 3;
    int scol = l & 7;
    int nk = K >> 6;
    for (int kt = 0; kt < nk; ++kt) {
#pragma unroll
        for (int j = 0; j < 4; ++j) {
            int seg = w * 4 + j;
            int row = seg * 8 + srow;
            int cg = scol ^ (row & 7);
            async_load16(A + (size_t)(m0 + row) * K + kt * 64 + cg * 8, As + seg * 512);
        }
#pragma unroll
        for (int j = 0; j < 4; ++j) {
            int seg = w * 4 + j;
            int row = seg * 8 + srow;
            int cg = scol ^ (row & 7);
            async_load16(Bt + (size_t)(n0 + row) * K + kt * 64 + cg * 8, Bs + seg * 512);
        }
        __syncthreads();
#pragma unroll
        for (int ks = 0; ks < 2; ++ks) {
            s16x8 af[4], bf[4];
#pragma unroll
            for (int mi = 0; mi < 4; ++mi) {
                int r = wm + mi * 16 + lane16;
                int ch = (ks * 4 + quad) ^ (r & 7);
                af[mi] = *(const s16x8*)&As[r * 64 + ch * 8];
            }
#pragma unroll
            for (int ni = 0; ni < 4; ++ni) {
                int r = wn + ni * 16 + lane16;
                int ch = (ks * 4 + quad) ^ (r & 7);
                bf[ni] = *(const s16x8*)&Bs[r * 64 + ch * 8];
            }
#pragma unroll
            for (int mi = 0; mi < 4; ++mi)
#pragma unroll
                for (int ni = 0; ni < 4; ++ni)
                    acc[mi][ni] = __builtin_amdgcn_mfma_f32_16x16x32_bf16(af[mi], bf[ni], acc[mi][ni], 0, 0, 0);
        }
        __syncthreads();
    }
#pragma unroll
    for (int ni = 0; ni < 4; ++ni) {
        int col = n0 + wn + ni * 16 + lane16;
        float bv = BIAS ? bias[col] : 0.0f;
#pragma unroll
        for (int mi = 0; mi < 4; ++mi) {
#pragma unroll
            for (int r = 0; r < 4; ++r) {
                int rowg = m0 + wm + mi * 16 + quad * 4 + r;
                float v = acc[mi][ni][r] + bv;
                if (OUTBF16)
                    ((u16*)Cout)[(size_t)rowg * N + col] = f2bf(v);
                else
                    ((float*)Cout)[(size_t)rowg * N + col] = v;
            }
        }
    }
}

// ---------------- 256x256 8-wave double-buffered counted-vmcnt MFMA GEMM -------------
// Use ONLY when grid <= 256 blocks (single scheduling round). ~120-140us per round.
template <bool BIAS, bool OUTBF16>
__global__ __launch_bounds__(512, 2) void gemm256_kernel(const u16* __restrict__ A,
                                                         const u16* __restrict__ Bt,
                                                         const float* __restrict__ bias,
                                                         void* __restrict__ Cout,
                                                         int M, int N, int K) {
    __shared__ __align__(16) u16 As[2 * 256 * 64];
    __shared__ __align__(16) u16 Bs[2 * 256 * 64];
    int t = threadIdx.x;
    int w = t >> 6, l = t & 63;
    int lane16 = l & 15, quad = l >> 4;
    int m0 = blockIdx.y * 256, n0 = blockIdx.x * 256;
    int wm2 = w >> 2, wn4 = w & 3;   // 2 x 4 wave grid

    f32x4 z = {0.f, 0.f, 0.f, 0.f};
    f32x4 acc[8][4];
#pragma unroll
    for (int i = 0; i < 8; ++i)
#pragma unroll
        for (int j = 0; j < 4; ++j) acc[i][j] = z;

    auto STAGE = [&](int p, int kt) {
        const u16* ak = A + kt * 64;
        const u16* bk = Bt + kt * 64;
#pragma unroll
        for (int j = 0; j < 4; ++j) {
            int idx = j * 512 + t;
            int row = idx >> 3;
            int cg = (idx & 7) ^ (row & 7);
            async_load16(ak + (size_t)(m0 + row) * K + cg * 8,
                         As + p * 16384 + j * 4096 + w * 512);
        }
#pragma unroll
        for (int j = 0; j < 4; ++j) {
            int idx = j * 512 + t;
            int row = idx >> 3;
            int cg = (idx & 7) ^ (row & 7);
            async_load16(bk + (size_t)(n0 + row) * K + cg * 8,
                         Bs + p * 16384 + j * 4096 + w * 512);
        }
    };

    auto COMPUTE = [&](int p) {
        const u16* Asp = As + p * 16384;
        const u16* Bsp = Bs + p * 16384;
#pragma unroll
        for (int mh = 0; mh < 2; ++mh) {
            s16x8 af[4][2];
#pragma unroll
            for (int mi = 0; mi < 4; ++mi) {
                int r = wm2 * 128 + mh * 64 + mi * 16 + lane16;
#pragma unroll
                for (int ks = 0; ks < 2; ++ks) {
                    int ch = (ks * 4 + quad) ^ (r & 7);
                    af[mi][ks] = *(const s16x8*)&Asp[r * 64 + ch * 8];
                }
            }
#pragma unroll
            for (int nh = 0; nh < 2; ++nh) {
                s16x8 bfr[2][2];
#pragma unroll
                for (int ni = 0; ni < 2; ++ni) {
                    int r = wn4 * 64 + nh * 32 + ni * 16 + lane16;
#pragma unroll
                    for (int ks = 0; ks < 2; ++ks) {
                        int ch = (ks * 4 + quad) ^ (r & 7);
                        bfr[ni][ks] = *(const s16x8*)&Bsp[r * 64 + ch * 8];
                    }
                }
                __builtin_amdgcn_s_setprio(1);
#pragma unroll
                for (int ks = 0; ks < 2; ++ks)
#pragma unroll
                    for (int mi = 0; mi < 4; ++mi)
#pragma unroll
                        for (int ni = 0; ni < 2; ++ni)
                            acc[mh * 4 + mi][nh * 2 + ni] = __builtin_amdgcn_mfma_f32_16x16x32_bf16(
                                af[mi][ks], bfr[ni][ks], acc[mh * 4 + mi][nh * 2 + ni], 0, 0, 0);
                __builtin_amdgcn_s_setprio(0);
            }
        }
    };

    int nk = K >> 6;
    STAGE(0, 0);
#pragma unroll 1
    for (int kt = 0; kt < nk; ++kt) {
        int p = kt & 1;
        if (kt + 1 < nk) {
            STAGE(p ^ 1, kt + 1);                              // next tile in flight
            asm volatile("s_waitcnt vmcnt(8)" ::: "memory");   // tile kt done; kt+1 stays in flight
        } else {
            asm volatile("s_waitcnt vmcnt(0)" ::: "memory");
        }
        __builtin_amdgcn_s_barrier();          // all waves' tile-kt loads landed
        __builtin_amdgcn_sched_barrier(0);     // no ds_read hoists above the barrier
        COMPUTE(p);
        asm volatile("s_waitcnt lgkmcnt(0)" ::: "memory");
        __builtin_amdgcn_s_barrier();          // all waves done reading buf p
    }

#pragma unroll
    for (int nj = 0; nj < 4; ++nj) {
        int col = n0 + wn4 * 64 + nj * 16 + lane16;
        float bv = BIAS ? bias[col] : 0.0f;
#pragma unroll
        for (int mj = 0; mj < 8; ++mj) {
#pragma unroll
            for (int r = 0; r < 4; ++r) {
                int rowg = m0 + wm2 * 128 + mj * 16 + quad * 4 + r;
                float v = acc[mj][nj][r] + bv;
                if (OUTBF16)
                    ((u16*)Cout)[(size_t)rowg * N + col] = f2bf(v);
                else
                    ((float*)Cout)[(size_t)rowg * N + col] = v;
            }
        }
    }
}

// ---------------- RoPE (Q,K) — fully vectorized u16x8 path ----------------
// Per row: 64 lanes build the sincos table in LDS once; then 256 threads map to
// (head 0..31, 8-elem group): 28 Q heads + 4 K heads, all 16B loads/stores.
__global__ __launch_bounds__(256) void rope_kernel(const u16* __restrict__ qkv,
                                                   const int* __restrict__ positions,
                                                   u16* __restrict__ Q, u16* __restrict__ Kout) {
    __shared__ float cs_s[64], sn_s[64];
    int row = blockIdx.x;           // b*S + s
    int b = row >> 11, s = row & 2047;
    int t = threadIdx.x;
    if (t < 64) {
        float pos = (float)positions[row];
        float freq = exp2f((float)(2 * t) * (-13.287712379549449f / 128.0f));
        float sn, cs;
        sincosf(pos * freq, &sn, &cs);
        cs_s[t] = cs; sn_s[t] = sn;
    }
    __syncthreads();
    int h = t >> 3, j = t & 7;      // h 0..31, j 0..7 (dims j*8 .. j*8+7)
    const u16* qrow = qkv + (size_t)row * QKV_N;
    bool isq = h < 28;
    const u16* src = isq ? (qrow + h * HD) : (qrow + QSZ + (h - 28) * HD);
    u16x8 a = *(const u16x8*)(src + j * 8);
    u16x8 bv = *(const u16x8*)(src + 64 + j * 8);
    float scale = isq ? RSCALE : 1.0f;
    u16x8 o1, o2;
#pragma unroll
    for (int e = 0; e < 8; ++e) {
        int d = j * 8 + e;
        float cs = cs_s[d], sn = sn_s[d];
        float x1 = bf2f(a[e]), x2 = bf2f(bv[e]);
        o1[e] = f2bf((x1 * cs - x2 * sn) * scale);
        o2[e] = f2bf((x2 * cs + x1 * sn) * scale);
    }
    u16* dst = isq ? (Q + ((size_t)(b * NH + h) * S_LEN + s) * HD)
                   : (Kout + ((size_t)(b * NKV + (h - 28)) * S_LEN + s) * HD);
    *(u16x8*)(dst + j * 8) = o1;
    *(u16x8*)(dst + 64 + j * 8) = o2;
}

// ---------------- V transpose: qkv[:, QSZ+KVSZ:] -> Vt[b][c][s] (u16, LDS-tiled) ----------------
__global__ __launch_bounds__(256) void vtrans_kernel(const u16* __restrict__ qkv,
                                                     u16* __restrict__ Vt) {
    __shared__ u16 T[64 * 72];
    int t = threadIdx.x;
    int c0 = blockIdx.x * 64, s0 = blockIdx.y * 64, b = blockIdx.z;
    const u16* src = qkv + (size_t)b * 2048 * QKV_N + QSZ + KVSZ + c0;
#pragma unroll
    for (int i = 0; i < 2; ++i) {
        int idx = i * 256 + t;
        int sr = idx >> 3, ch = idx & 7;
        u16x8 v = *(const u16x8*)&src[(size_t)(s0 + sr) * QKV_N + ch * 8];
#pragma unroll
        for (int j = 0; j < 8; ++j) T[(ch * 8 + j) * 72 + sr] = v[j];
    }
    __syncthreads();
    u16* dst = Vt + (size_t)b * 512 * 2048;
#pragma unroll
    for (int i = 0; i < 2; ++i) {
        int idx = i * 256 + t;
        int cr = idx >> 3, ch = idx & 7;
        *(u16x8*)&dst[(size_t)(c0 + cr) * 2048 + s0 + ch * 8] = *(const u16x8*)&T[cr * 72 + ch * 8];
    }
}

// ---------------- flash attention (causal, GQA-fused) — round-4 exact (best measured) ----
__global__ __launch_bounds__(512, 2) void attn_kernel(const u16* __restrict__ Q,
                                                      const u16* __restrict__ K,
                                                      const u16* __restrict__ Vt,
                                                      u16* __restrict__ O) {
    __shared__ __align__(16) u16 Ks[64 * 128];
    __shared__ __align__(16) u16 Vs[128 * 64];
    __shared__ __align__(16) u16 Ps[7 * 16 * 72];
    int p = blockIdx.x;             // 0..31  (q-tile pair)
    int bh = blockIdx.y;            // b*4 + hk
    int b = bh >> 2, hk = bh & 3;
    int t = threadIdx.x, w = t >> 6, l = t & 63;
    int lane16 = l & 15, quad = l >> 4;
    const u16* Kb = K + (size_t)(b * NKV + hk) * S_LEN * HD;
    const u16* Vb = Vt + (size_t)(b * NKV + hk) * HD * S_LEN;
    int wc = (w < 7) ? w : 6;       // clamp so wave 7's pointer math stays in-bounds
    int h = hk * 7 + wc;
    const u16* Qb = Q + (size_t)(b * NH + h) * S_LEN * HD;
    u16* Pw = Ps + wc * (16 * 72);

    u16x8 kr[2], vr_[2];
    auto stageR = [&](int kt) {
#pragma unroll
        for (int j = 0; j < 2; ++j) {
            int idx = j * 512 + t;
            kr[j] = *(const u16x8*)&Kb[(size_t)(kt * 64 + (idx >> 4)) * HD + (idx & 15) * 8];
        }
#pragma unroll
        for (int j = 0; j < 2; ++j) {
            int idx = j * 512 + t;
            vr_[j] = *(const u16x8*)&Vb[(size_t)(idx >> 3) * S_LEN + kt * 64 + (idx & 7) * 8];
        }
    };
    auto dsw = [&]() {
#pragma unroll
        for (int j = 0; j < 2; ++j) {
            int idx = j * 512 + t;
            int row = idx >> 4, c = idx & 15;
            *(u16x8*)&Ks[row * 128 + (c ^ (row & 15)) * 8] = kr[j];
        }
#pragma unroll
        for (int j = 0; j < 2; ++j) {
            int idx = j * 512 + t;
            int row = idx >> 3, c = idx & 7;
            *(u16x8*)&Vs[row * 64 + (c ^ (row & 7)) * 8] = vr_[j];
        }
    };

    f32x4 z = {0.f, 0.f, 0.f, 0.f};

#pragma unroll 1
    for (int phase = 0; phase < 2; ++phase) {
        int q0 = (phase == 0) ? p * 32 : (63 - p) * 32;
        int nkt = (q0 >> 6) + 1;

        s16x8 qf[2][4];
        if (w < 7) {
#pragma unroll
            for (int st = 0; st < 2; ++st) {
                int qrow = q0 + st * 16 + lane16;
#pragma unroll
                for (int kd = 0; kd < 4; ++kd)
                    qf[st][kd] = *(const s16x8*)(Qb + (size_t)qrow * HD + kd * 32 + quad * 8);
            }
        }
        f32x4 oacc[2][8];
        float m_r[2][4], l_r[2][4];
#pragma unroll
        for (int st = 0; st < 2; ++st) {
#pragma unroll
            for (int i = 0; i < 8; ++i) oacc[st][i] = z;
#pragma unroll
            for (int r = 0; r < 4; ++r) { m_r[st][r] = -3.0e38f; l_r[st][r] = 0.f; }
        }

        stageR(0);
#pragma unroll 1
        for (int kt = 0; kt < nkt; ++kt) {
            __syncthreads();                 // all waves done reading previous tile
            dsw();                           // LDS <- regs (tile kt)
            __syncthreads();
            if (kt + 1 < nkt) stageR(kt + 1);  // issue next tile's global loads now
            if (w < 7) {
#pragma unroll
                for (int st = 0; st < 2; ++st) {
                    f32x4 sa[4];
                    sa[0] = z; sa[1] = z; sa[2] = z; sa[3] = z;
#pragma unroll
                    for (int kd = 0; kd < 4; ++kd) {
#pragma unroll
                        for (int ni = 0; ni < 4; ++ni) {
                            int srow = ni * 16 + lane16;
                            int ch = (kd * 4 + quad) ^ lane16;
                            s16x8 kf = *(const s16x8*)&Ks[srow * 128 + ch * 8];
                            sa[ni] = __builtin_amdgcn_mfma_f32_16x16x32_bf16(qf[st][kd], kf, sa[ni], 0, 0, 0);
                        }
                    }
                    if (kt == nkt - 1) {
#pragma unroll
                        for (int ni = 0; ni < 4; ++ni)
#pragma unroll
                            for (int r = 0; r < 4; ++r) {
                                int colg = kt * 64 + ni * 16 + lane16;
                                int rowg = q0 + st * 16 + quad * 4 + r;
                                if (colg > rowg) sa[ni][r] = -3.0e38f;
                            }
                    }
                    float mx[4];
#pragma unroll
                    for (int r = 0; r < 4; ++r) {
                        mx[r] = fmaxf(fmaxf(sa[0][r], sa[1][r]), fmaxf(sa[2][r], sa[3][r]));
                        mx[r] = fmaxf(mx[r], __shfl_xor(mx[r], 1));
                        mx[r] = fmaxf(mx[r], __shfl_xor(mx[r], 2));
                        mx[r] = fmaxf(mx[r], __shfl_xor(mx[r], 4));
                        mx[r] = fmaxf(mx[r], __shfl_xor(mx[r], 8));
                    }
                    float al[4], rs[4], pp[4][4];
#pragma unroll
                    for (int r = 0; r < 4; ++r) {
                        float mn = fmaxf(m_r[st][r], mx[r]);
                        al[r] = __expf(m_r[st][r] - mn);
                        m_r[st][r] = mn;
                        rs[r] = 0.f;
                    }
#pragma unroll
                    for (int ni = 0; ni < 4; ++ni)
#pragma unroll
                        for (int r = 0; r < 4; ++r) {
                            pp[ni][r] = __expf(sa[ni][r] - m_r[st][r]);
                            rs[r] += pp[ni][r];
                        }
#pragma unroll
                    for (int r = 0; r < 4; ++r) {
                        rs[r] += __shfl_xor(rs[r], 1);
                        rs[r] += __shfl_xor(rs[r], 2);
                        rs[r] += __shfl_xor(rs[r], 4);
                        rs[r] += __shfl_xor(rs[r], 8);
                        l_r[st][r] = l_r[st][r] * al[r] + rs[r];
                    }
#pragma unroll
                    for (int i = 0; i < 8; ++i)
#pragma unroll
                        for (int r = 0; r < 4; ++r) oacc[st][i][r] *= al[r];
                    // P: C-layout -> A-layout via per-wave LDS region
#pragma unroll
                    for (int ni = 0; ni < 4; ++ni)
#pragma unroll
                        for (int r = 0; r < 4; ++r)
                            Pw[(quad * 4 + r) * 72 + ni * 16 + lane16] = f2bf(pp[ni][r]);
#pragma unroll
                    for (int ks = 0; ks < 2; ++ks) {
                        s16x8 pf = *(const s16x8*)&Pw[lane16 * 72 + ks * 32 + quad * 8];
#pragma unroll
                        for (int ni2 = 0; ni2 < 8; ++ni2) {
                            int vr = ni2 * 16 + lane16;
                            int ch = (ks * 4 + quad) ^ (vr & 7);
                            s16x8 vf = *(const s16x8*)&Vs[vr * 64 + ch * 8];
                            oacc[st][ni2] = __builtin_amdgcn_mfma_f32_16x16x32_bf16(pf, vf, oacc[st][ni2], 0, 0, 0);
                        }
                    }
                }
            }
        }
        // epilogue for this q-tile
        if (w < 7) {
#pragma unroll
            for (int st = 0; st < 2; ++st) {
                float inv[4];
#pragma unroll
                for (int r = 0; r < 4; ++r) inv[r] = 1.0f / l_r[st][r];
#pragma unroll
                for (int ni2 = 0; ni2 < 8; ++ni2)
#pragma unroll
                    for (int r = 0; r < 4; ++r) {
                        int rowg = q0 + st * 16 + quad * 4 + r;
                        int colg = h * HD + ni2 * 16 + lane16;
                        O[((size_t)b * S_LEN + rowg) * QSZ + colg] = f2bf(oacc[st][ni2][r] * inv[r]);
                    }
            }
        }
    }
}

extern "C" void kernel_launch(void* const* d_in, const int* in_sizes, int n_in,
                              void* d_out, int out_size, void* d_ws, size_t ws_size,
                              hipStream_t stream) {
    const int* positions = (const int*)d_in[0];
    const float* hs = (const float*)d_in[1];
    const float* Wqkv = (const float*)d_in[2];
    const float* bqkv = (const float*)d_in[3];
    const float* Wo = (const float*)d_in[4];
    float* out = (float*)d_out;
    char* ws = (char*)d_ws;

    u16* hsb   = (u16*)(ws + 0);          // later reused as Q
    u16* Wqkvt = (u16*)(ws + 29360128);
    u16* Wot   = (u16*)(ws + 62390272);
    u16* qkv   = (u16*)(ws + 88080384);   // later reused as attn out
    u16* Kbuf  = (u16*)(ws + 125829120);
    u16* Vtb   = (u16*)(ws + 130023424);
    u16* Qbuf  = hsb;
    u16* attn  = qkv;

    hipLaunchKernelGGL(cvt_bf16_kernel, dim3(14336), dim3(256), 0, stream, hs, hsb, 3670016);
    hipLaunchKernelGGL(transpose_cvt_kernel, dim3(144, 56), dim3(256), 0, stream, Wqkv, Wqkvt, 3584, 4608);
    hipLaunchKernelGGL(transpose_cvt_kernel, dim3(112, 56), dim3(256), 0, stream, Wo, Wot, 3584, 3584);
    // QKV split to kill the 288-block tail: cols [0,4096) = 16x16 = EXACTLY 256
    // gemm256 blocks (one full scheduling round), cols [4096,4608) = 4x32 = 128
    // gemm-128^2 blocks (partial round, ~46us).
    hipLaunchKernelGGL((gemm256_kernel<true, true>), dim3(16, 16), dim3(512), 0, stream,
                       hsb, Wqkvt, bqkv, (void*)qkv, 4096, 4608, 3584);
    hipLaunchKernelGGL((gemm_kernel<true, true>), dim3(4, 32), dim3(256), 0, stream,
                       hsb, Wqkvt + (size_t)4096 * 3584, bqkv + 4096, (void*)(qkv + 4096),
                       4096, 4608, 3584);
    hipLaunchKernelGGL(rope_kernel, dim3(4096), dim3(256), 0, stream, qkv, positions, Qbuf, Kbuf);
    hipLaunchKernelGGL(vtrans_kernel, dim3(8, 32, 2), dim3(256), 0, stream, qkv, Vtb);
    hipLaunchKernelGGL(attn_kernel, dim3(32, 8), dim3(512), 0, stream, Qbuf, Kbuf, Vtb, attn);
    // Out-proj: 224 tiles < 256 CUs -> single round.
    hipLaunchKernelGGL((gemm256_kernel<false, false>), dim3(14, 16), dim3(512), 0, stream,
                       attn, Wot, (const float*)nullptr, (void*)out, 4096, 3584, 3584);
}

// Round 9
// 641.096 us; speedup vs baseline: 1.0288x; 1.0288x over previous
//
#include <hip/hip_runtime.h>
#include <stdint.h>

typedef unsigned short u16;
typedef short s16x8 __attribute__((ext_vector_type(8)));
typedef unsigned short u16x8 __attribute__((ext_vector_type(8)));
typedef float f32x4 __attribute__((ext_vector_type(4)));

#define S_LEN 2048
#define NBATCH 2
#define HID 3584
#define NH 28
#define NKV 4
#define HD 128
#define QSZ 3584
#define KVSZ 512
#define QKV_N 4608
#define RSCALE 0.08838834764831845f  // 128^-0.5

__device__ __forceinline__ u16 f2bf(float f) {
    union { float f; uint32_t u; } x; x.f = f;
    uint32_t r = x.u + 0x7FFF + ((x.u >> 16) & 1);
    return (u16)(r >> 16);
}
__device__ __forceinline__ float bf2f(u16 u) {
    union { uint32_t u; float f; } x; x.u = ((uint32_t)u) << 16;
    return x.f;
}
__device__ __forceinline__ void async_load16(const u16* g, u16* l) {
    __builtin_amdgcn_global_load_lds((const __attribute__((address_space(1))) void*)g,
                                     (__attribute__((address_space(3))) void*)l, 16, 0, 0);
}

// ---------------- fused prep: fp32->bf16 cvt + both weight transposes ----------------
// One launch replaces three (removes two ramp/drain cycles + launch gaps).
// blocks [0,14336): cvt hs; [14336,22400): transpose Wqkv; [22400,28672): transpose Wo.
__device__ __forceinline__ void trans_tile(const float* __restrict__ in, u16* __restrict__ out,
                                           int R, int C, int bx, int by, int t,
                                           float (*tile)[33]) {
    int r0 = by * 64, c0 = bx * 32;
    int lr = t >> 3, lc = (t & 7) * 4;
#pragma unroll
    for (int i = 0; i < 2; ++i) {
        int rr = lr + i * 32;
        float4 v = *(const float4*)&in[(size_t)(r0 + rr) * C + c0 + lc];
        tile[rr][lc + 0] = v.x; tile[rr][lc + 1] = v.y;
        tile[rr][lc + 2] = v.z; tile[rr][lc + 3] = v.w;
    }
    __syncthreads();
    int wr = t >> 3, wc = (t & 7) * 8;
    u16x8 o;
#pragma unroll
    for (int e = 0; e < 8; ++e) o[e] = f2bf(tile[wc + e][wr]);
    *(u16x8*)&out[(size_t)(c0 + wr) * R + r0 + wc] = o;
}

__global__ __launch_bounds__(256) void prep_kernel(const float* __restrict__ hs, u16* __restrict__ hsb,
                                                   const float* __restrict__ Wqkv, u16* __restrict__ Wqkvt,
                                                   const float* __restrict__ Wo, u16* __restrict__ Wot) {
    __shared__ float tile[64][33];
    int bid = blockIdx.x;
    int t = threadIdx.x;
    if (bid < 14336) {
        int i = bid * 256 + t;
        float4 v = ((const float4*)hs)[i];
        ushort4 o;
        o.x = f2bf(v.x); o.y = f2bf(v.y); o.z = f2bf(v.z); o.w = f2bf(v.w);
        ((ushort4*)hsb)[i] = o;
    } else if (bid < 22400) {
        int idx = bid - 14336;
        trans_tile(Wqkv, Wqkvt, 3584, 4608, idx % 144, idx / 144, t, tile);
    } else {
        int idx = bid - 22400;
        trans_tile(Wo, Wot, 3584, 3584, idx % 112, idx / 112, t, tile);
    }
}

// ---------------- 128x128 4-wave MFMA GEMM ----------
template <bool BIAS, bool OUTBF16>
__global__ __launch_bounds__(256) void gemm_kernel(const u16* __restrict__ A,
                                                   const u16* __restrict__ Bt,
                                                   const float* __restrict__ bias,
                                                   void* __restrict__ Cout,
                                                   int M, int N, int K) {
    __shared__ __align__(16) u16 As[128 * 64];
    __shared__ __align__(16) u16 Bs[128 * 64];
    int t = threadIdx.x;
    int w = t >> 6, l = t & 63;
    int lane16 = l & 15, quad = l >> 4;
    int m0 = blockIdx.y * 128, n0 = blockIdx.x * 128;
    int wm = (w >> 1) * 64, wn = (w & 1) * 64;

    f32x4 z = {0.f, 0.f, 0.f, 0.f};
    f32x4 acc[4][4];
#pragma unroll
    for (int i = 0; i < 4; ++i)
#pragma unroll
        for (int j = 0; j < 4; ++j) acc[i][j] = z;

    int srow = l >> 3;
    int scol = l & 7;
    int nk = K >> 6;
    for (int kt = 0; kt < nk; ++kt) {
#pragma unroll
        for (int j = 0; j < 4; ++j) {
            int seg = w * 4 + j;
            int row = seg * 8 + srow;
            int cg = scol ^ (row & 7);
            async_load16(A + (size_t)(m0 + row) * K + kt * 64 + cg * 8, As + seg * 512);
        }
#pragma unroll
        for (int j = 0; j < 4; ++j) {
            int seg = w * 4 + j;
            int row = seg * 8 + srow;
            int cg = scol ^ (row & 7);
            async_load16(Bt + (size_t)(n0 + row) * K + kt * 64 + cg * 8, Bs + seg * 512);
        }
        __syncthreads();
#pragma unroll
        for (int ks = 0; ks < 2; ++ks) {
            s16x8 af[4], bf[4];
#pragma unroll
            for (int mi = 0; mi < 4; ++mi) {
                int r = wm + mi * 16 + lane16;
                int ch = (ks * 4 + quad) ^ (r & 7);
                af[mi] = *(const s16x8*)&As[r * 64 + ch * 8];
            }
#pragma unroll
            for (int ni = 0; ni < 4; ++ni) {
                int r = wn + ni * 16 + lane16;
                int ch = (ks * 4 + quad) ^ (r & 7);
                bf[ni] = *(const s16x8*)&Bs[r * 64 + ch * 8];
            }
#pragma unroll
            for (int mi = 0; mi < 4; ++mi)
#pragma unroll
                for (int ni = 0; ni < 4; ++ni)
                    acc[mi][ni] = __builtin_amdgcn_mfma_f32_16x16x32_bf16(af[mi], bf[ni], acc[mi][ni], 0, 0, 0);
        }
        __syncthreads();
    }
#pragma unroll
    for (int ni = 0; ni < 4; ++ni) {
        int col = n0 + wn + ni * 16 + lane16;
        float bv = BIAS ? bias[col] : 0.0f;
#pragma unroll
        for (int mi = 0; mi < 4; ++mi) {
#pragma unroll
            for (int r = 0; r < 4; ++r) {
                int rowg = m0 + wm + mi * 16 + quad * 4 + r;
                float v = acc[mi][ni][r] + bv;
                if (OUTBF16)
                    ((u16*)Cout)[(size_t)rowg * N + col] = f2bf(v);
                else
                    ((float*)Cout)[(size_t)rowg * N + col] = v;
            }
        }
    }
}

// ---------------- V-producing GEMM: computes qkv cols [4096,4608) and writes Vt[b][c][s]
// directly (transposed epilogue) — vtrans kernel deleted. ----------
__global__ __launch_bounds__(256) void gemm_v_kernel(const u16* __restrict__ A,
                                                     const u16* __restrict__ Bt,
                                                     const float* __restrict__ bias,
                                                     u16* __restrict__ Vt, int K) {
    __shared__ __align__(16) u16 As[128 * 64];
    __shared__ __align__(16) u16 Bs[128 * 64];
    int t = threadIdx.x;
    int w = t >> 6, l = t & 63;
    int lane16 = l & 15, quad = l >> 4;
    int m0 = blockIdx.y * 128, n0 = blockIdx.x * 128;
    int wm = (w >> 1) * 64, wn = (w & 1) * 64;

    f32x4 z = {0.f, 0.f, 0.f, 0.f};
    f32x4 acc[4][4];
#pragma unroll
    for (int i = 0; i < 4; ++i)
#pragma unroll
        for (int j = 0; j < 4; ++j) acc[i][j] = z;

    int srow = l >> 3;
    int scol = l & 7;
    int nk = K >> 6;
    for (int kt = 0; kt < nk; ++kt) {
#pragma unroll
        for (int j = 0; j < 4; ++j) {
            int seg = w * 4 + j;
            int row = seg * 8 + srow;
            int cg = scol ^ (row & 7);
            async_load16(A + (size_t)(m0 + row) * K + kt * 64 + cg * 8, As + seg * 512);
        }
#pragma unroll
        for (int j = 0; j < 4; ++j) {
            int seg = w * 4 + j;
            int row = seg * 8 + srow;
            int cg = scol ^ (row & 7);
            async_load16(Bt + (size_t)(n0 + row) * K + kt * 64 + cg * 8, Bs + seg * 512);
        }
        __syncthreads();
#pragma unroll
        for (int ks = 0; ks < 2; ++ks) {
            s16x8 af[4], bf[4];
#pragma unroll
            for (int mi = 0; mi < 4; ++mi) {
                int r = wm + mi * 16 + lane16;
                int ch = (ks * 4 + quad) ^ (r & 7);
                af[mi] = *(const s16x8*)&As[r * 64 + ch * 8];
            }
#pragma unroll
            for (int ni = 0; ni < 4; ++ni) {
                int r = wn + ni * 16 + lane16;
                int ch = (ks * 4 + quad) ^ (r & 7);
                bf[ni] = *(const s16x8*)&Bs[r * 64 + ch * 8];
            }
#pragma unroll
            for (int mi = 0; mi < 4; ++mi)
#pragma unroll
                for (int ni = 0; ni < 4; ++ni)
                    acc[mi][ni] = __builtin_amdgcn_mfma_f32_16x16x32_bf16(af[mi], bf[ni], acc[mi][ni], 0, 0, 0);
        }
        __syncthreads();
    }
    // transposed epilogue: Vt[b][col][s], rows quad*4+r are 4 consecutive s values
#pragma unroll
    for (int ni = 0; ni < 4; ++ni) {
        int col = n0 + wn + ni * 16 + lane16;      // 0..511 (V channel)
        float bv = bias[col];
#pragma unroll
        for (int mi = 0; mi < 4; ++mi) {
            int rowg = m0 + wm + mi * 16 + quad * 4;   // multiple of 4
            int b = rowg >> 11, s = rowg & 2047;
            ushort4 o;
            o.x = f2bf(acc[mi][ni][0] + bv);
            o.y = f2bf(acc[mi][ni][1] + bv);
            o.z = f2bf(acc[mi][ni][2] + bv);
            o.w = f2bf(acc[mi][ni][3] + bv);
            *(ushort4*)&Vt[(size_t)b * 512 * 2048 + (size_t)col * 2048 + s] = o;
        }
    }
}

// ---------------- 256x256 8-wave double-buffered counted-vmcnt MFMA GEMM -------------
// Use ONLY when grid <= 256 blocks (single scheduling round). ~120-140us per round.
template <bool BIAS, bool OUTBF16>
__global__ __launch_bounds__(512, 2) void gemm256_kernel(const u16* __restrict__ A,
                                                         const u16* __restrict__ Bt,
                                                         const float* __restrict__ bias,
                                                         void* __restrict__ Cout,
                                                         int M, int N, int K) {
    __shared__ __align__(16) u16 As[2 * 256 * 64];
    __shared__ __align__(16) u16 Bs[2 * 256 * 64];
    int t = threadIdx.x;
    int w = t >> 6, l = t & 63;
    int lane16 = l & 15, quad = l >> 4;
    int m0 = blockIdx.y * 256, n0 = blockIdx.x * 256;
    int wm2 = w >> 2, wn4 = w & 3;   // 2 x 4 wave grid

    f32x4 z = {0.f, 0.f, 0.f, 0.f};
    f32x4 acc[8][4];
#pragma unroll
    for (int i = 0; i < 8; ++i)
#pragma unroll
        for (int j = 0; j < 4; ++j) acc[i][j] = z;

    auto STAGE = [&](int p, int kt) {
        const u16* ak = A + kt * 64;
        const u16* bk = Bt + kt * 64;
#pragma unroll
        for (int j = 0; j < 4; ++j) {
            int idx = j * 512 + t;
            int row = idx >> 3;
            int cg = (idx & 7) ^ (row & 7);
            async_load16(ak + (size_t)(m0 + row) * K + cg * 8,
                         As + p * 16384 + j * 4096 + w * 512);
        }
#pragma unroll
        for (int j = 0; j < 4; ++j) {
            int idx = j * 512 + t;
            int row = idx >> 3;
            int cg = (idx & 7) ^ (row & 7);
            async_load16(bk + (size_t)(n0 + row) * K + cg * 8,
                         Bs + p * 16384 + j * 4096 + w * 512);
        }
    };

    auto COMPUTE = [&](int p) {
        const u16* Asp = As + p * 16384;
        const u16* Bsp = Bs + p * 16384;
#pragma unroll
        for (int mh = 0; mh < 2; ++mh) {
            s16x8 af[4][2];
#pragma unroll
            for (int mi = 0; mi < 4; ++mi) {
                int r = wm2 * 128 + mh * 64 + mi * 16 + lane16;
#pragma unroll
                for (int ks = 0; ks < 2; ++ks) {
                    int ch = (ks * 4 + quad) ^ (r & 7);
                    af[mi][ks] = *(const s16x8*)&Asp[r * 64 + ch * 8];
                }
            }
#pragma unroll
            for (int nh = 0; nh < 2; ++nh) {
                s16x8 bfr[2][2];
#pragma unroll
                for (int ni = 0; ni < 2; ++ni) {
                    int r = wn4 * 64 + nh * 32 + ni * 16 + lane16;
#pragma unroll
                    for (int ks = 0; ks < 2; ++ks) {
                        int ch = (ks * 4 + quad) ^ (r & 7);
                        bfr[ni][ks] = *(const s16x8*)&Bsp[r * 64 + ch * 8];
                    }
                }
                __builtin_amdgcn_s_setprio(1);
#pragma unroll
                for (int ks = 0; ks < 2; ++ks)
#pragma unroll
                    for (int mi = 0; mi < 4; ++mi)
#pragma unroll
                        for (int ni = 0; ni < 2; ++ni)
                            acc[mh * 4 + mi][nh * 2 + ni] = __builtin_amdgcn_mfma_f32_16x16x32_bf16(
                                af[mi][ks], bfr[ni][ks], acc[mh * 4 + mi][nh * 2 + ni], 0, 0, 0);
                __builtin_amdgcn_s_setprio(0);
            }
        }
    };

    int nk = K >> 6;
    STAGE(0, 0);
#pragma unroll 1
    for (int kt = 0; kt < nk; ++kt) {
        int p = kt & 1;
        if (kt + 1 < nk) {
            STAGE(p ^ 1, kt + 1);                              // next tile in flight
            asm volatile("s_waitcnt vmcnt(8)" ::: "memory");   // tile kt done; kt+1 stays in flight
        } else {
            asm volatile("s_waitcnt vmcnt(0)" ::: "memory");
        }
        __builtin_amdgcn_s_barrier();          // all waves' tile-kt loads landed
        __builtin_amdgcn_sched_barrier(0);     // no ds_read hoists above the barrier
        COMPUTE(p);
        asm volatile("s_waitcnt lgkmcnt(0)" ::: "memory");
        __builtin_amdgcn_s_barrier();          // all waves done reading buf p
    }

#pragma unroll
    for (int nj = 0; nj < 4; ++nj) {
        int col = n0 + wn4 * 64 + nj * 16 + lane16;
        float bv = BIAS ? bias[col] : 0.0f;
#pragma unroll
        for (int mj = 0; mj < 8; ++mj) {
#pragma unroll
            for (int r = 0; r < 4; ++r) {
                int rowg = m0 + wm2 * 128 + mj * 16 + quad * 4 + r;
                float v = acc[mj][nj][r] + bv;
                if (OUTBF16)
                    ((u16*)Cout)[(size_t)rowg * N + col] = f2bf(v);
                else
                    ((float*)Cout)[(size_t)rowg * N + col] = v;
            }
        }
    }
}

// ---------------- RoPE (Q,K) — fully vectorized u16x8 path ----------------
__global__ __launch_bounds__(256) void rope_kernel(const u16* __restrict__ qkv,
                                                   const int* __restrict__ positions,
                                                   u16* __restrict__ Q, u16* __restrict__ Kout) {
    __shared__ float cs_s[64], sn_s[64];
    int row = blockIdx.x;           // b*S + s
    int b = row >> 11, s = row & 2047;
    int t = threadIdx.x;
    if (t < 64) {
        float pos = (float)positions[row];
        float freq = exp2f((float)(2 * t) * (-13.287712379549449f / 128.0f));
        float sn, cs;
        sincosf(pos * freq, &sn, &cs);
        cs_s[t] = cs; sn_s[t] = sn;
    }
    __syncthreads();
    int h = t >> 3, j = t & 7;      // h 0..31, j 0..7
    const u16* qrow = qkv + (size_t)row * QKV_N;
    bool isq = h < 28;
    const u16* src = isq ? (qrow + h * HD) : (qrow + QSZ + (h - 28) * HD);
    u16x8 a = *(const u16x8*)(src + j * 8);
    u16x8 bv = *(const u16x8*)(src + 64 + j * 8);
    float scale = isq ? RSCALE : 1.0f;
    u16x8 o1, o2;
#pragma unroll
    for (int e = 0; e < 8; ++e) {
        int d = j * 8 + e;
        float cs = cs_s[d], sn = sn_s[d];
        float x1 = bf2f(a[e]), x2 = bf2f(bv[e]);
        o1[e] = f2bf((x1 * cs - x2 * sn) * scale);
        o2[e] = f2bf((x2 * cs + x1 * sn) * scale);
    }
    u16* dst = isq ? (Q + ((size_t)(b * NH + h) * S_LEN + s) * HD)
                   : (Kout + ((size_t)(b * NKV + (h - 28)) * S_LEN + s) * HD);
    *(u16x8*)(dst + j * 8) = o1;
    *(u16x8*)(dst + 64 + j * 8) = o2;
}

// ---------------- flash attention (causal, GQA-fused) — round-7 version (best measured:
// <=138.5us). Defer-max (T13) + MFMA row-sum for l. ----------
__global__ __launch_bounds__(512, 2) void attn_kernel(const u16* __restrict__ Q,
                                                      const u16* __restrict__ K,
                                                      const u16* __restrict__ Vt,
                                                      u16* __restrict__ O) {
    __shared__ __align__(16) u16 Ks[64 * 128];
    __shared__ __align__(16) u16 Vs[128 * 64];
    __shared__ __align__(16) u16 Ps[7 * 16 * 72];
    int p = blockIdx.x;             // 0..31  (q-tile pair)
    int bh = blockIdx.y;            // b*4 + hk
    int b = bh >> 2, hk = bh & 3;
    int t = threadIdx.x, w = t >> 6, l = t & 63;
    int lane16 = l & 15, quad = l >> 4;
    const u16* Kb = K + (size_t)(b * NKV + hk) * S_LEN * HD;
    const u16* Vb = Vt + (size_t)(b * NKV + hk) * HD * S_LEN;
    int wc = (w < 7) ? w : 6;       // clamp so wave 7's pointer math stays in-bounds
    int h = hk * 7 + wc;
    const u16* Qb = Q + (size_t)(b * NH + h) * S_LEN * HD;
    u16* Pw = Ps + wc * (16 * 72);

    const s16x8 onesv = {0x3F80, 0x3F80, 0x3F80, 0x3F80, 0x3F80, 0x3F80, 0x3F80, 0x3F80};

    u16x8 kr[2], vr_[2];
    auto stageR = [&](int kt) {
#pragma unroll
        for (int j = 0; j < 2; ++j) {
            int idx = j * 512 + t;
            kr[j] = *(const u16x8*)&Kb[(size_t)(kt * 64 + (idx >> 4)) * HD + (idx & 15) * 8];
        }
#pragma unroll
        for (int j = 0; j < 2; ++j) {
            int idx = j * 512 + t;
            vr_[j] = *(const u16x8*)&Vb[(size_t)(idx >> 3) * S_LEN + kt * 64 + (idx & 7) * 8];
        }
    };
    auto dsw = [&]() {
#pragma unroll
        for (int j = 0; j < 2; ++j) {
            int idx = j * 512 + t;
            int row = idx >> 4, c = idx & 15;
            *(u16x8*)&Ks[row * 128 + (c ^ (row & 15)) * 8] = kr[j];
        }
#pragma unroll
        for (int j = 0; j < 2; ++j) {
            int idx = j * 512 + t;
            int row = idx >> 3, c = idx & 7;
            *(u16x8*)&Vs[row * 64 + (c ^ (row & 7)) * 8] = vr_[j];
        }
    };

    f32x4 z = {0.f, 0.f, 0.f, 0.f};

#pragma unroll 1
    for (int phase = 0; phase < 2; ++phase) {
        int q0 = (phase == 0) ? p * 32 : (63 - p) * 32;
        int nkt = (q0 >> 6) + 1;

        s16x8 qf[2][4];
        if (w < 7) {
#pragma unroll
            for (int st = 0; st < 2; ++st) {
                int qrow = q0 + st * 16 + lane16;
#pragma unroll
                for (int kd = 0; kd < 4; ++kd)
                    qf[st][kd] = *(const s16x8*)(Qb + (size_t)qrow * HD + kd * 32 + quad * 8);
            }
        }
        f32x4 oacc[2][8];
        f32x4 acc_l[2];
        float m_r[2][4];
#pragma unroll
        for (int st = 0; st < 2; ++st) {
#pragma unroll
            for (int i = 0; i < 8; ++i) oacc[st][i] = z;
            acc_l[st] = z;
#pragma unroll
            for (int r = 0; r < 4; ++r) m_r[st][r] = -3.0e38f;
        }

        stageR(0);
#pragma unroll 1
        for (int kt = 0; kt < nkt; ++kt) {
            __syncthreads();                 // all waves done reading previous tile
            dsw();                           // LDS <- regs (tile kt)
            __syncthreads();
            if (kt + 1 < nkt) stageR(kt + 1);  // issue next tile's global loads now
            if (w < 7) {
#pragma unroll
                for (int st = 0; st < 2; ++st) {
                    f32x4 sa[4];
                    sa[0] = z; sa[1] = z; sa[2] = z; sa[3] = z;
#pragma unroll
                    for (int kd = 0; kd < 4; ++kd) {
#pragma unroll
                        for (int ni = 0; ni < 4; ++ni) {
                            int srow = ni * 16 + lane16;
                            int ch = (kd * 4 + quad) ^ lane16;
                            s16x8 kf = *(const s16x8*)&Ks[srow * 128 + ch * 8];
                            sa[ni] = __builtin_amdgcn_mfma_f32_16x16x32_bf16(qf[st][kd], kf, sa[ni], 0, 0, 0);
                        }
                    }
                    if (kt == nkt - 1) {
#pragma unroll
                        for (int ni = 0; ni < 4; ++ni)
#pragma unroll
                            for (int r = 0; r < 4; ++r) {
                                int colg = kt * 64 + ni * 16 + lane16;
                                int rowg = q0 + st * 16 + quad * 4 + r;
                                if (colg > rowg) sa[ni][r] = -3.0e38f;
                            }
                    }
                    float mx[4];
#pragma unroll
                    for (int r = 0; r < 4; ++r) {
                        mx[r] = fmaxf(fmaxf(sa[0][r], sa[1][r]), fmaxf(sa[2][r], sa[3][r]));
                        mx[r] = fmaxf(mx[r], __shfl_xor(mx[r], 1));
                        mx[r] = fmaxf(mx[r], __shfl_xor(mx[r], 2));
                        mx[r] = fmaxf(mx[r], __shfl_xor(mx[r], 4));
                        mx[r] = fmaxf(mx[r], __shfl_xor(mx[r], 8));
                    }
                    // T13 defer-max: only rescale when some row's max grew by > 8
                    int ok = (mx[0] <= m_r[st][0] + 8.0f) && (mx[1] <= m_r[st][1] + 8.0f) &&
                             (mx[2] <= m_r[st][2] + 8.0f) && (mx[3] <= m_r[st][3] + 8.0f);
                    if (!__all(ok)) {
                        float al[4];
#pragma unroll
                        for (int r = 0; r < 4; ++r) {
                            float mn = fmaxf(m_r[st][r], mx[r]);
                            al[r] = __expf(m_r[st][r] - mn);
                            m_r[st][r] = mn;
                        }
#pragma unroll
                        for (int i = 0; i < 8; ++i)
#pragma unroll
                            for (int r = 0; r < 4; ++r) oacc[st][i][r] *= al[r];
#pragma unroll
                        for (int r = 0; r < 4; ++r) acc_l[st][r] *= al[r];
                    }
                    float pp[4][4];
#pragma unroll
                    for (int ni = 0; ni < 4; ++ni)
#pragma unroll
                        for (int r = 0; r < 4; ++r)
                            pp[ni][r] = __expf(sa[ni][r] - m_r[st][r]);
                    // P: C-layout -> A-layout via per-wave LDS region
#pragma unroll
                    for (int ni = 0; ni < 4; ++ni)
#pragma unroll
                        for (int r = 0; r < 4; ++r)
                            Pw[(quad * 4 + r) * 72 + ni * 16 + lane16] = f2bf(pp[ni][r]);
#pragma unroll
                    for (int ks = 0; ks < 2; ++ks) {
                        s16x8 pf = *(const s16x8*)&Pw[lane16 * 72 + ks * 32 + quad * 8];
                        // l row-sum via MFMA (B = ones): D[row][*] = sum_k P[row][k]
                        acc_l[st] = __builtin_amdgcn_mfma_f32_16x16x32_bf16(pf, onesv, acc_l[st], 0, 0, 0);
#pragma unroll
                        for (int ni2 = 0; ni2 < 8; ++ni2) {
                            int vr = ni2 * 16 + lane16;
                            int ch = (ks * 4 + quad) ^ (vr & 7);
                            s16x8 vf = *(const s16x8*)&Vs[vr * 64 + ch * 8];
                            oacc[st][ni2] = __builtin_amdgcn_mfma_f32_16x16x32_bf16(pf, vf, oacc[st][ni2], 0, 0, 0);
                        }
                    }
                }
            }
        }
        // epilogue for this q-tile
        if (w < 7) {
#pragma unroll
            for (int st = 0; st < 2; ++st) {
                float inv[4];
#pragma unroll
                for (int r = 0; r < 4; ++r) inv[r] = 1.0f / acc_l[st][r];
#pragma unroll
                for (int ni2 = 0; ni2 < 8; ++ni2)
#pragma unroll
                    for (int r = 0; r < 4; ++r) {
                        int rowg = q0 + st * 16 + quad * 4 + r;
                        int colg = h * HD + ni2 * 16 + lane16;
                        O[((size_t)b * S_LEN + rowg) * QSZ + colg] = f2bf(oacc[st][ni2][r] * inv[r]);
                    }
            }
        }
    }
}

extern "C" void kernel_launch(void* const* d_in, const int* in_sizes, int n_in,
                              void* d_out, int out_size, void* d_ws, size_t ws_size,
                              hipStream_t stream) {
    const int* positions = (const int*)d_in[0];
    const float* hs = (const float*)d_in[1];
    const float* Wqkv = (const float*)d_in[2];
    const float* bqkv = (const float*)d_in[3];
    const float* Wo = (const float*)d_in[4];
    float* out = (float*)d_out;
    char* ws = (char*)d_ws;

    u16* hsb   = (u16*)(ws + 0);          // cvt output; later overwritten by Q (rope)
    u16* Wqkvt = (u16*)(ws + 29360128);
    u16* Wot   = (u16*)(ws + 62390272);
    u16* qkv   = (u16*)(ws + 88080384);   // Q|K cols only; later reused as attn out
    u16* Kbuf  = (u16*)(ws + 125829120);
    u16* Vtb   = (u16*)(ws + 130023424);
    u16* Qbuf  = hsb;
    u16* attn  = qkv;

    // 1. fused prep: cvt + both weight transposes (was 3 launches)
    hipLaunchKernelGGL(prep_kernel, dim3(28672), dim3(256), 0, stream,
                       hs, hsb, Wqkv, Wqkvt, Wo, Wot);
    // 2. QKV cols [0,4096) = Q|K: exactly 256 gemm256 blocks (one full round)
    hipLaunchKernelGGL((gemm256_kernel<true, true>), dim3(16, 16), dim3(512), 0, stream,
                       hsb, Wqkvt, bqkv, (void*)qkv, 4096, 4608, 3584);
    // 3. QKV cols [4096,4608) = V: 128-tile GEMM writing Vt[b][c][s] directly
    hipLaunchKernelGGL(gemm_v_kernel, dim3(4, 32), dim3(256), 0, stream,
                       hsb, Wqkvt + (size_t)4096 * 3584, bqkv + 4096, Vtb, 3584);
    // 4. RoPE Q,K (vectorized)
    hipLaunchKernelGGL(rope_kernel, dim3(4096), dim3(256), 0, stream, qkv, positions, Qbuf, Kbuf);
    // 5. attention
    hipLaunchKernelGGL(attn_kernel, dim3(32, 8), dim3(512), 0, stream, Qbuf, Kbuf, Vtb, attn);
    // 6. out-proj: 224 tiles < 256 CUs -> single round
    hipLaunchKernelGGL((gemm256_kernel<false, false>), dim3(14, 16), dim3(512), 0, stream,
                       attn, Wot, (const float*)nullptr, (void*)out, 4096, 3584, 3584);
}